// Round 1
// baseline (2479.805 us; speedup 1.0000x reference)
//
#include <hip/hip_runtime.h>
#include <math.h>

#define Hh 4
#define Bb 32
#define Tt 1000
#define EPROJS_ 1024
#define DUNITS_ 1024
#define DKd 512
#define DVd 512
#define CC 100
#define KMAX 201
#define SCALING 0.04419417382415922f  // 1/sqrt(512)

// ---------------- WW[h,k,e] = sum_c conv_w_h[c,k] * Watt[h,c,e] ----------------
__global__ __launch_bounds__(256) void ww_kernel(
    const float* __restrict__ w0, const float* __restrict__ w1,
    const float* __restrict__ w2, const float* __restrict__ w3,
    const float* __restrict__ Watt, float* __restrict__ WWp)
{
    int k = blockIdx.x;           // 0..200
    int h = blockIdx.y;           // 0..3
    int f = 25 * (h + 1);
    int Kh = 2 * f + 1;
    if (k >= Kh) return;
    const float* cw = (h == 0) ? w0 : (h == 1) ? w1 : (h == 2) ? w2 : w3;
    int e = threadIdx.x;          // 0..255 (handles e and e+256)
    float acc0 = 0.f, acc1 = 0.f;
    for (int c = 0; c < CC; ++c) {
        float wv = cw[c * Kh + k];
        acc0 += wv * Watt[(h * CC + c) * DKd + e];
        acc1 += wv * Watt[(h * CC + c) * DKd + e + 256];
    }
    WWp[(h * KMAX + k) * DKd + e] = acc0;
    WWp[(h * KMAX + k) * DKd + e + 256] = acc1;
}

// ---------------- q[h,b,e] = dec_z[b,:] . Wq[h,:,e]  (bq added in e_kernel) ----
__global__ __launch_bounds__(256) void q_kernel(
    const float* __restrict__ dec_z, const float* __restrict__ Wq,
    float* __restrict__ q_buf)
{
    int e = blockIdx.x * 256 + threadIdx.x;   // 0..511
    int d0 = blockIdx.y * 256;                // 4 chunks of 256
    int h = blockIdx.z;
    float acc[32];
#pragma unroll
    for (int b = 0; b < 32; ++b) acc[b] = 0.f;
    for (int d = d0; d < d0 + 256; ++d) {
        float wq = Wq[(h * DUNITS_ + d) * DKd + e];
#pragma unroll
        for (int b = 0; b < 32; ++b) acc[b] += dec_z[b * DUNITS_ + d] * wq;
    }
#pragma unroll
    for (int b = 0; b < 32; ++b)
        atomicAdd(&q_buf[(h * Bb + b) * DKd + e], acc[b]);
}

// ---------------- e[h,b,t] = sum_e g_w[h,e]*tanh(K + loc + q + bq) -------------
// 128x128 tile GEMM over two K-phases: (1) enc @ Wk[h] over d=1024,
// (2) banded att_prev window @ WW[h] over k=K_h. Epilogue fuses tanh-dot.
__global__ __launch_bounds__(256) void e_kernel(
    const float* __restrict__ enc, const float* __restrict__ Wk,
    const float* __restrict__ att_prev, const float* __restrict__ WWp,
    const float* __restrict__ q_buf, const float* __restrict__ bq,
    const float* __restrict__ g_w, float* __restrict__ e_buf)
{
    const int bx = blockIdx.x;   // col block 0..3  (e0)
    const int by = blockIdx.y;   // t tile 0..7
    const int bz = blockIdx.z;   // h*32 + b
    const int h = bz >> 5, b = bz & 31;
    const int t0 = by * 128;
    const int e0 = bx * 128;
    const int tid = threadIdx.x;
    const int ty = tid >> 4, tx = tid & 15;

    __shared__ float As[16 * 132];   // [kk][t_local], padded
    __shared__ float Bs[16 * 132];   // [kk][e_local], padded

    float acc[8][8];
#pragma unroll
    for (int i = 0; i < 8; ++i)
#pragma unroll
        for (int j = 0; j < 8; ++j) acc[i][j] = 0.f;

    const int row = tid >> 1;        // 0..127 A-load row
    const int half = tid & 1;        // which 8 of the 16 k's

    // ---- phase 1: d-contraction (64 chunks of 16) ----
    const float* Bbase = Wk + (size_t)h * EPROJS_ * DKd;
    for (int ch = 0; ch < 64; ++ch) {
        int d0 = ch * 16;
        float4 av0 = {0,0,0,0}, av1 = {0,0,0,0};
        if (t0 + row < Tt) {
            const float* p = enc + ((size_t)(b * Tt + t0 + row)) * EPROJS_ + d0 + half * 8;
            av0 = *(const float4*)p;
            av1 = *(const float4*)(p + 4);
        }
        const float* bp = Bbase + (d0 + ty) * DKd + e0 + tx * 8;
        float4 bv0 = *(const float4*)bp;
        float4 bv1 = *(const float4*)(bp + 4);
        __syncthreads();
        {
            int kb = half * 8;
            As[(kb + 0) * 132 + row] = av0.x;
            As[(kb + 1) * 132 + row] = av0.y;
            As[(kb + 2) * 132 + row] = av0.z;
            As[(kb + 3) * 132 + row] = av0.w;
            As[(kb + 4) * 132 + row] = av1.x;
            As[(kb + 5) * 132 + row] = av1.y;
            As[(kb + 6) * 132 + row] = av1.z;
            As[(kb + 7) * 132 + row] = av1.w;
            *(float4*)&Bs[ty * 132 + tx * 8] = bv0;
            *(float4*)&Bs[ty * 132 + tx * 8 + 4] = bv1;
        }
        __syncthreads();
#pragma unroll
        for (int kk = 0; kk < 16; ++kk) {
            float4 a0 = *(float4*)&As[kk * 132 + ty * 8];
            float4 a1 = *(float4*)&As[kk * 132 + ty * 8 + 4];
            float4 c0 = *(float4*)&Bs[kk * 132 + tx * 8];
            float4 c1 = *(float4*)&Bs[kk * 132 + tx * 8 + 4];
            float a[8] = {a0.x, a0.y, a0.z, a0.w, a1.x, a1.y, a1.z, a1.w};
            float bb[8] = {c0.x, c0.y, c0.z, c0.w, c1.x, c1.y, c1.z, c1.w};
#pragma unroll
            for (int i = 0; i < 8; ++i)
#pragma unroll
                for (int j = 0; j < 8; ++j) acc[i][j] += a[i] * bb[j];
        }
    }

    // ---- phase 2: banded location term, k-contraction over K_h ----
    const int f = 25 * (h + 1);
    const int Kh = 2 * f + 1;
    const int nch = (Kh + 15) >> 4;
    const float* abase2 = att_prev + (h * Bb + b) * Tt;
    const float* Bbase2 = WWp + h * (KMAX * DKd);
    for (int ch = 0; ch < nch; ++ch) {
        int k0 = ch * 16;
        float a8[8];
#pragma unroll
        for (int j = 0; j < 8; ++j) {
            int s = t0 + row - f + k0 + half * 8 + j;
            a8[j] = (s >= 0 && s < Tt) ? abase2[s] : 0.f;
        }
        float4 bv0 = {0,0,0,0}, bv1 = {0,0,0,0};
        if (k0 + ty < Kh) {
            const float* bp = Bbase2 + (k0 + ty) * DKd + e0 + tx * 8;
            bv0 = *(const float4*)bp;
            bv1 = *(const float4*)(bp + 4);
        }
        __syncthreads();
        {
            int kb = half * 8;
#pragma unroll
            for (int j = 0; j < 8; ++j) As[(kb + j) * 132 + row] = a8[j];
            *(float4*)&Bs[ty * 132 + tx * 8] = bv0;
            *(float4*)&Bs[ty * 132 + tx * 8 + 4] = bv1;
        }
        __syncthreads();
#pragma unroll
        for (int kk = 0; kk < 16; ++kk) {
            float4 a0 = *(float4*)&As[kk * 132 + ty * 8];
            float4 a1 = *(float4*)&As[kk * 132 + ty * 8 + 4];
            float4 c0 = *(float4*)&Bs[kk * 132 + tx * 8];
            float4 c1 = *(float4*)&Bs[kk * 132 + tx * 8 + 4];
            float a[8] = {a0.x, a0.y, a0.z, a0.w, a1.x, a1.y, a1.z, a1.w};
            float bb[8] = {c0.x, c0.y, c0.z, c0.w, c1.x, c1.y, c1.z, c1.w};
#pragma unroll
            for (int i = 0; i < 8; ++i)
#pragma unroll
                for (int j = 0; j < 8; ++j) acc[i][j] += a[i] * bb[j];
        }
    }

    // ---- epilogue: +q+bq, tanh, *g_w, row-reduce over 128 cols, atomicAdd ----
    float qv[8], gw[8];
#pragma unroll
    for (int j = 0; j < 8; ++j) {
        int e = e0 + tx * 8 + j;
        qv[j] = q_buf[(h * Bb + b) * DKd + e] + bq[h * DKd + e];
        gw[j] = g_w[h * DKd + e];
    }
#pragma unroll
    for (int i = 0; i < 8; ++i) {
        float s = 0.f;
#pragma unroll
        for (int j = 0; j < 8; ++j) s += tanhf(acc[i][j] + qv[j]) * gw[j];
        s += __shfl_xor(s, 1, 16);
        s += __shfl_xor(s, 2, 16);
        s += __shfl_xor(s, 4, 16);
        s += __shfl_xor(s, 8, 16);
        int t = t0 + ty * 8 + i;
        if (tx == 0 && t < Tt)
            atomicAdd(&e_buf[(h * Bb + b) * Tt + t], s);
    }
}

// ---------------- w = softmax(scaling * e) over T ------------------------------
__global__ __launch_bounds__(256) void softmax_kernel(
    const float* __restrict__ e_buf, float* __restrict__ wout)
{
    int rowid = blockIdx.x;                // h*32+b, 0..127
    const float* x = e_buf + rowid * Tt;
    float* y = wout + rowid * Tt;
    int tid = threadIdx.x;
    float v[4];
    float m = -1e30f;
#pragma unroll
    for (int k = 0; k < 4; ++k) {
        int t = tid + k * 256;
        v[k] = (t < Tt) ? x[t] * SCALING : -1e30f;
        m = fmaxf(m, v[k]);
    }
    for (int off = 32; off >= 1; off >>= 1) m = fmaxf(m, __shfl_xor(m, off));
    __shared__ float sm[4];
    __shared__ float ss[4];
    int wave = tid >> 6;
    if ((tid & 63) == 0) sm[wave] = m;
    __syncthreads();
    m = fmaxf(fmaxf(sm[0], sm[1]), fmaxf(sm[2], sm[3]));
    float s = 0.f;
#pragma unroll
    for (int k = 0; k < 4; ++k) {
        int t = tid + k * 256;
        v[k] = (t < Tt) ? __expf(v[k] - m) : 0.f;
        s += v[k];
    }
    for (int off = 32; off >= 1; off >>= 1) s += __shfl_xor(s, off);
    if ((tid & 63) == 0) ss[wave] = s;
    __syncthreads();
    s = ss[0] + ss[1] + ss[2] + ss[3];
    float inv = 1.0f / s;
#pragma unroll
    for (int k = 0; k < 4; ++k) {
        int t = tid + k * 256;
        if (t < Tt) y[t] = v[k] * inv;
    }
}

// ---------------- ctx[h,b,d] = sum_t w[h,b,t] * enc[b,t,d] --------------------
__global__ __launch_bounds__(256) void ctx_kernel(
    const float* __restrict__ wout, const float* __restrict__ enc,
    float* __restrict__ ctx)
{
    int dch = blockIdx.x;    // 0..7: 128-float d chunk
    int b = blockIdx.y;      // 0..31
    int tid = threadIdx.x;
    __shared__ float wl[4 * Tt];
    __shared__ float red[8 * 4 * 128];
    for (int i = tid; i < 4 * Tt; i += 256) {
        int h = i / Tt, t = i - h * Tt;
        wl[i] = wout[(h * Bb + b) * Tt + t];
    }
    __syncthreads();
    int g = tid >> 5, c = tid & 31;
    int d0 = dch * 128;
    float4 a[4];
#pragma unroll
    for (int h = 0; h < 4; ++h) a[h] = make_float4(0.f, 0.f, 0.f, 0.f);
    for (int t = g; t < Tt; t += 8) {
        float4 ev = *(const float4*)(enc + ((size_t)(b * Tt + t)) * EPROJS_ + d0 + c * 4);
#pragma unroll
        for (int h = 0; h < 4; ++h) {
            float wv = wl[h * Tt + t];
            a[h].x += wv * ev.x; a[h].y += wv * ev.y;
            a[h].z += wv * ev.z; a[h].w += wv * ev.w;
        }
    }
#pragma unroll
    for (int h = 0; h < 4; ++h)
        *(float4*)&red[((g * 4 + h) << 7) + c * 4] = a[h];
    __syncthreads();
    for (int i = tid; i < 512; i += 256) {
        int h = i >> 7, dd = i & 127;
        float ssum = 0.f;
#pragma unroll
        for (int g2 = 0; g2 < 8; ++g2) ssum += red[((g2 * 4 + h) << 7) + dd];
        ctx[(h * Bb + b) * EPROJS_ + d0 + dd] = ssum;
    }
}

// ---------------- c[h,b,e] = sum_d ctx[h,b,d] * Wv[h,d,e] ---------------------
__global__ __launch_bounds__(256) void c_kernel(
    const float* __restrict__ ctx, const float* __restrict__ Wv,
    float* __restrict__ c_buf)
{
    int e = blockIdx.x * 256 + threadIdx.x;   // 0..511
    int d0 = blockIdx.y * 128;                // 8 chunks
    int h = blockIdx.z;
    float acc[32];
#pragma unroll
    for (int b = 0; b < 32; ++b) acc[b] = 0.f;
    for (int d = d0; d < d0 + 128; ++d) {
        float wv = Wv[(h * EPROJS_ + d) * DVd + e];
#pragma unroll
        for (int b = 0; b < 32; ++b) acc[b] += ctx[(h * Bb + b) * EPROJS_ + d] * wv;
    }
#pragma unroll
    for (int b = 0; b < 32; ++b)
        atomicAdd(&c_buf[(h * Bb + b) * DVd + e], acc[b]);
}

// ---------------- out[b,o] = sum_{h,e} c[h,b,e] * Wo[h*512+e, o] --------------
__global__ __launch_bounds__(256) void out_kernel(
    const float* __restrict__ c_buf, const float* __restrict__ Wo,
    float* __restrict__ outp)
{
    int o = blockIdx.x * 256 + threadIdx.x;   // 0..1023
    int k0 = blockIdx.y * 256;                // 8 chunks of (h,e)
    float acc[32];
#pragma unroll
    for (int b = 0; b < 32; ++b) acc[b] = 0.f;
    for (int k = k0; k < k0 + 256; ++k) {
        int h = k >> 9, e = k & 511;
        float wo = Wo[(size_t)k * EPROJS_ + o];
#pragma unroll
        for (int b = 0; b < 32; ++b) acc[b] += c_buf[(h * Bb + b) * DVd + e] * wo;
    }
#pragma unroll
    for (int b = 0; b < 32; ++b)
        atomicAdd(&outp[b * EPROJS_ + o], acc[b]);
}

extern "C" void kernel_launch(void* const* d_in, const int* in_sizes, int n_in,
                              void* d_out, int out_size, void* d_ws, size_t ws_size,
                              hipStream_t stream) {
    const float* enc     = (const float*)d_in[0];
    const float* dec_z   = (const float*)d_in[2];
    const float* att_prev= (const float*)d_in[3];
    const float* Wq      = (const float*)d_in[4];
    const float* bq      = (const float*)d_in[5];
    const float* Wk      = (const float*)d_in[6];
    const float* Wv      = (const float*)d_in[7];
    const float* g_w     = (const float*)d_in[8];
    const float* Watt    = (const float*)d_in[10];
    const float* Wo      = (const float*)d_in[11];
    const float* cw0     = (const float*)d_in[12];
    const float* cw1     = (const float*)d_in[13];
    const float* cw2     = (const float*)d_in[14];
    const float* cw3     = (const float*)d_in[15];

    float* ws    = (float*)d_ws;
    float* q_buf = ws;                        // 65536
    float* e_buf = ws + 65536;                // 128000
    float* c_buf = ws + 193536;               // 65536
    float* ctx   = ws + 259072;               // 131072
    float* WWp   = ws + 390144;               // 4*201*512 = 411648
    float* outp  = (float*)d_out;             // 32768
    float* wout  = outp + 32768;              // 128000

    // zero the atomic-accumulated buffers (q, e, c) and the out region
    hipMemsetAsync(ws, 0, (size_t)259072 * sizeof(float), stream);
    hipMemsetAsync(d_out, 0, (size_t)32768 * sizeof(float), stream);

    ww_kernel<<<dim3(KMAX, 4), 256, 0, stream>>>(cw0, cw1, cw2, cw3, Watt, WWp);
    q_kernel<<<dim3(2, 4, 4), 256, 0, stream>>>(dec_z, Wq, q_buf);
    e_kernel<<<dim3(4, 8, 128), 256, 0, stream>>>(enc, Wk, att_prev, WWp,
                                                  q_buf, bq, g_w, e_buf);
    softmax_kernel<<<128, 256, 0, stream>>>(e_buf, wout);
    ctx_kernel<<<dim3(8, 32), 256, 0, stream>>>(wout, enc, ctx);
    c_kernel<<<dim3(2, 8, 4), 256, 0, stream>>>(ctx, Wv, c_buf);
    out_kernel<<<dim3(4, 8), 256, 0, stream>>>(c_buf, Wo, outp);
}

// Round 2
// 1110.109 us; speedup vs baseline: 2.2338x; 2.2338x over previous
//
#include <hip/hip_runtime.h>
#include <hip/hip_bf16.h>
#include <math.h>

#define Hh 4
#define Bb 32
#define Tt 1000
#define EPROJS_ 1024
#define DUNITS_ 1024
#define DKd 512
#define DVd 512
#define CC 100
#define KPAD 224
#define SCALING 0.04419417382415922f  // 1/sqrt(512)

typedef __attribute__((ext_vector_type(8))) short short8;
typedef __attribute__((ext_vector_type(4))) float floatx4;

__device__ __forceinline__ void async16(const void* g, void* l) {
    __builtin_amdgcn_global_load_lds(
        (const __attribute__((address_space(1))) unsigned int*)g,
        (__attribute__((address_space(3))) unsigned int*)l, 16, 0, 0);
}

// ---------------- Wkt[h][e][d] = bf16(Wk[h][d][e]) -----------------------------
__global__ __launch_bounds__(256) void wkt_kernel(
    const float* __restrict__ Wk, __hip_bfloat16* __restrict__ Wkt)
{
    int et = blockIdx.x;   // 0..15
    int dt = blockIdx.y;   // 0..31
    int h  = blockIdx.z;
    __shared__ float tile[32][33];
    int c = threadIdx.x & 31, r8 = threadIdx.x >> 5;
    const float* src = Wk + ((size_t)h * EPROJS_ + dt * 32) * DKd + et * 32;
#pragma unroll
    for (int rr = 0; rr < 4; ++rr) {
        int dl = r8 * 4 + rr;
        tile[dl][c] = src[(size_t)dl * DKd + c];
    }
    __syncthreads();
    __hip_bfloat16* dst = Wkt + ((size_t)h * DKd + et * 32) * EPROJS_ + dt * 32;
#pragma unroll
    for (int rr = 0; rr < 4; ++rr) {
        int el = r8 * 4 + rr;
        dst[(size_t)el * EPROJS_ + c] = __float2bfloat16(tile[c][el]);
    }
}

// ---------------- WWt[h][e][k] = bf16(sum_c cw_h[c,k]*Watt[h,c,e]), pad to 224 --
__global__ __launch_bounds__(256) void ww_kernel(
    const float* __restrict__ w0, const float* __restrict__ w1,
    const float* __restrict__ w2, const float* __restrict__ w3,
    const float* __restrict__ Watt, __hip_bfloat16* __restrict__ WWt)
{
    int e = blockIdx.x * 256 + threadIdx.x;   // 0..511
    int h = blockIdx.y;
    int kc = blockIdx.z;                      // 0..6
    int f = 25 * (h + 1), Kh = 2 * f + 1;
    const float* cw = (h == 0) ? w0 : (h == 1) ? w1 : (h == 2) ? w2 : w3;
    const float* Wb = Watt + (size_t)h * CC * DKd + e;
    __hip_bfloat16* out = WWt + ((size_t)h * DKd + e) * KPAD;
    for (int k = kc * 32; k < kc * 32 + 32; ++k) {
        float acc = 0.f;
        if (k < Kh)
            for (int c2 = 0; c2 < CC; ++c2)
                acc += cw[c2 * Kh + k] * Wb[(size_t)c2 * DKd];
        out[k] = __float2bfloat16(acc);
    }
}

// ---------------- q[h,b,e] = dec_z[b,:] . Wq[h,:,e] ---------------------------
__global__ __launch_bounds__(256) void q_kernel(
    const float* __restrict__ dec_z, const float* __restrict__ Wq,
    float* __restrict__ q_buf)
{
    int e = blockIdx.x * 256 + threadIdx.x;
    int d0 = blockIdx.y * 256;
    int h = blockIdx.z;
    float acc[32];
#pragma unroll
    for (int b = 0; b < 32; ++b) acc[b] = 0.f;
    for (int d = d0; d < d0 + 256; ++d) {
        float wq = Wq[(h * DUNITS_ + d) * DKd + e];
#pragma unroll
        for (int b = 0; b < 32; ++b) acc[b] += dec_z[b * DUNITS_ + d] * wq;
    }
#pragma unroll
    for (int b = 0; b < 32; ++b)
        atomicAdd(&q_buf[(h * Bb + b) * DKd + e], acc[b]);
}

// ---------------- e[h,b,t]: MFMA bf16 GEMM + fused tanh-dot epilogue -----------
__global__ __launch_bounds__(256) void e_kernel(
    const float* __restrict__ enc, const __hip_bfloat16* __restrict__ Wkt,
    const float* __restrict__ att_prev, const __hip_bfloat16* __restrict__ WWt,
    const float* __restrict__ q_buf, const float* __restrict__ bq,
    const float* __restrict__ g_w, float* __restrict__ e_buf)
{
    const int bx = blockIdx.x;   // e0 block 0..3
    const int by = blockIdx.y;   // t tile 0..7
    const int bz = blockIdx.z;   // h*32+b
    const int h = bz >> 5, b = bz & 31;
    const int t0 = by * 128, e0 = bx * 128;
    const int tid = threadIdx.x;
    const int lane = tid & 63, w = tid >> 6;
    const int wr = w >> 1, wc = w & 1;
    const int m = lane & 15, quad = lane >> 4;

    __shared__ __align__(16) short As[128 * 32];
    __shared__ __align__(16) short Bs[128 * 32];

    floatx4 acc[4][4];
#pragma unroll
    for (int i = 0; i < 4; ++i)
#pragma unroll
        for (int j = 0; j < 4; ++j) acc[i][j] = (floatx4){0.f, 0.f, 0.f, 0.f};

    const __hip_bfloat16* WkB = Wkt + ((size_t)h * DKd + e0) * EPROJS_;
    const float* encB = enc + (size_t)b * Tt * EPROJS_;

    // ---- phase 1: K=1024 over d, BK=32 ----
    for (int ch = 0; ch < 32; ++ch) {
        int d0 = ch * 32;
        float4 a0[2], a1[2];
#pragma unroll
        for (int it = 0; it < 2; ++it) {
            int L = tid + it * 256;
            int rr = L >> 2, ko = (L & 3) * 8;
            int t = t0 + rr;
            float4 x0 = {0, 0, 0, 0}, x1 = {0, 0, 0, 0};
            if (t < Tt) {
                const float* p = encB + (size_t)t * EPROJS_ + d0 + ko;
                x0 = *(const float4*)p;
                x1 = *(const float4*)(p + 4);
            }
            a0[it] = x0; a1[it] = x1;
        }
        __syncthreads();   // previous tile's reads complete
#pragma unroll
        for (int it = 0; it < 2; ++it) {
            int L = tid + it * 256;
            int rr = L >> 2, ko = (L & 3) * 8;
            const __hip_bfloat16* gp = WkB + (size_t)rr * EPROJS_ + d0 + ko;
            async16(gp, (char*)Bs + (tid & ~63) * 16 + it * 4096);
        }
#pragma unroll
        for (int it = 0; it < 2; ++it) {
            int L = tid + it * 256;
            int rr = L >> 2, ko = (L & 3) * 8;
            union { short8 s; __hip_bfloat162 hh[4]; } u;
            u.hh[0] = __float22bfloat162_rn(make_float2(a0[it].x, a0[it].y));
            u.hh[1] = __float22bfloat162_rn(make_float2(a0[it].z, a0[it].w));
            u.hh[2] = __float22bfloat162_rn(make_float2(a1[it].x, a1[it].y));
            u.hh[3] = __float22bfloat162_rn(make_float2(a1[it].z, a1[it].w));
            *(short8*)&As[rr * 32 + ko] = u.s;
        }
        __syncthreads();   // drains vmcnt (async B) + lgkm (A writes)
        short8 af[4], bf[4];
#pragma unroll
        for (int i = 0; i < 4; ++i)
            af[i] = *(const short8*)&As[(wr * 64 + i * 16 + m) * 32 + quad * 8];
#pragma unroll
        for (int j = 0; j < 4; ++j)
            bf[j] = *(const short8*)&Bs[(wc * 64 + j * 16 + m) * 32 + quad * 8];
#pragma unroll
        for (int i = 0; i < 4; ++i)
#pragma unroll
            for (int j = 0; j < 4; ++j)
                acc[i][j] = __builtin_amdgcn_mfma_f32_16x16x32_bf16(
                    af[i], bf[j], acc[i][j], 0, 0, 0);
    }

    // ---- phase 2: banded location term over k, BK=32 ----
    const int f = 25 * (h + 1);
    const int Kh = 2 * f + 1;
    const int nch2 = (Kh + 31) >> 5;
    const float* ab = att_prev + (size_t)(h * Bb + b) * Tt;
    const __hip_bfloat16* WWB = WWt + ((size_t)h * DKd + e0) * KPAD;
    for (int ch = 0; ch < nch2; ++ch) {
        int k0 = ch * 32;
        int rr = tid >> 1, kh = (tid & 1) * 16;
        int sbase = t0 + rr - f + k0 + kh;
        float v[16];
#pragma unroll
        for (int j2 = 0; j2 < 16; ++j2) {
            int s = sbase + j2;
            v[j2] = (s >= 0 && s < Tt) ? ab[s] : 0.f;
        }
        __syncthreads();
#pragma unroll
        for (int it = 0; it < 2; ++it) {
            int L = tid + it * 256;
            int r2 = L >> 2, ko = (L & 3) * 8;
            const __hip_bfloat16* gp = WWB + (size_t)r2 * KPAD + k0 + ko;
            async16(gp, (char*)Bs + (tid & ~63) * 16 + it * 4096);
        }
        union { short8 s[2]; __hip_bfloat162 hh[8]; } u;
#pragma unroll
        for (int j2 = 0; j2 < 8; ++j2)
            u.hh[j2] = __float22bfloat162_rn(make_float2(v[2 * j2], v[2 * j2 + 1]));
        *(short8*)&As[rr * 32 + kh] = u.s[0];
        *(short8*)&As[rr * 32 + kh + 8] = u.s[1];
        __syncthreads();
        short8 af[4], bf[4];
#pragma unroll
        for (int i = 0; i < 4; ++i)
            af[i] = *(const short8*)&As[(wr * 64 + i * 16 + m) * 32 + quad * 8];
#pragma unroll
        for (int j = 0; j < 4; ++j)
            bf[j] = *(const short8*)&Bs[(wc * 64 + j * 16 + m) * 32 + quad * 8];
#pragma unroll
        for (int i = 0; i < 4; ++i)
#pragma unroll
            for (int j = 0; j < 4; ++j)
                acc[i][j] = __builtin_amdgcn_mfma_f32_16x16x32_bf16(
                    af[i], bf[j], acc[i][j], 0, 0, 0);
    }

    // ---- epilogue: +q+bq, tanh, *g_w, reduce 16 cols/quad, atomicAdd ----------
    const float* qrow = q_buf + (size_t)(h * Bb + b) * DKd;
    const float* bqrow = bq + h * DKd;
    const float* gwrow = g_w + h * DKd;
    float qv[4], gw[4];
#pragma unroll
    for (int j = 0; j < 4; ++j) {
        int e = e0 + wc * 64 + j * 16 + m;
        qv[j] = qrow[e] + bqrow[e];
        gw[j] = gwrow[e];
    }
    float* erow = e_buf + (size_t)(h * Bb + b) * Tt;
#pragma unroll
    for (int i = 0; i < 4; ++i) {
#pragma unroll
        for (int reg = 0; reg < 4; ++reg) {
            float s = 0.f;
#pragma unroll
            for (int j = 0; j < 4; ++j)
                s += tanhf(acc[i][j][reg] + qv[j]) * gw[j];
            s += __shfl_xor(s, 1);
            s += __shfl_xor(s, 2);
            s += __shfl_xor(s, 4);
            s += __shfl_xor(s, 8);
            int t = t0 + wr * 64 + i * 16 + quad * 4 + reg;
            if (m == 0 && t < Tt)
                atomicAdd(&erow[t], s);
        }
    }
}

// ---------------- w = softmax(scaling * e) over T ------------------------------
__global__ __launch_bounds__(256) void softmax_kernel(
    const float* __restrict__ e_buf, float* __restrict__ wout)
{
    int rowid = blockIdx.x;
    const float* x = e_buf + rowid * Tt;
    float* y = wout + rowid * Tt;
    int tid = threadIdx.x;
    float v[4];
    float mx = -1e30f;
#pragma unroll
    for (int k = 0; k < 4; ++k) {
        int t = tid + k * 256;
        v[k] = (t < Tt) ? x[t] * SCALING : -1e30f;
        mx = fmaxf(mx, v[k]);
    }
    for (int off = 32; off >= 1; off >>= 1) mx = fmaxf(mx, __shfl_xor(mx, off));
    __shared__ float sm[4];
    __shared__ float ss[4];
    int wave = tid >> 6;
    if ((tid & 63) == 0) sm[wave] = mx;
    __syncthreads();
    mx = fmaxf(fmaxf(sm[0], sm[1]), fmaxf(sm[2], sm[3]));
    float s = 0.f;
#pragma unroll
    for (int k = 0; k < 4; ++k) {
        int t = tid + k * 256;
        v[k] = (t < Tt) ? __expf(v[k] - mx) : 0.f;
        s += v[k];
    }
    for (int off = 32; off >= 1; off >>= 1) s += __shfl_xor(s, off);
    if ((tid & 63) == 0) ss[wave] = s;
    __syncthreads();
    s = ss[0] + ss[1] + ss[2] + ss[3];
    float inv = 1.0f / s;
#pragma unroll
    for (int k = 0; k < 4; ++k) {
        int t = tid + k * 256;
        if (t < Tt) y[t] = v[k] * inv;
    }
}

// ---------------- ctx[h,b,d] = sum_t w[h,b,t] * enc[b,t,d] --------------------
__global__ __launch_bounds__(256) void ctx_kernel(
    const float* __restrict__ wout, const float* __restrict__ enc,
    float* __restrict__ ctx)
{
    int dch = blockIdx.x;
    int b = blockIdx.y;
    int tid = threadIdx.x;
    __shared__ float wl[4 * Tt];
    __shared__ float red[8 * 4 * 128];
    for (int i = tid; i < 4 * Tt; i += 256) {
        int h = i / Tt, t = i - h * Tt;
        wl[i] = wout[(h * Bb + b) * Tt + t];
    }
    __syncthreads();
    int g = tid >> 5, c = tid & 31;
    int d0 = dch * 128;
    float4 a[4];
#pragma unroll
    for (int h = 0; h < 4; ++h) a[h] = make_float4(0.f, 0.f, 0.f, 0.f);
    for (int t = g; t < Tt; t += 8) {
        float4 ev = *(const float4*)(enc + ((size_t)(b * Tt + t)) * EPROJS_ + d0 + c * 4);
#pragma unroll
        for (int h = 0; h < 4; ++h) {
            float wv = wl[h * Tt + t];
            a[h].x += wv * ev.x; a[h].y += wv * ev.y;
            a[h].z += wv * ev.z; a[h].w += wv * ev.w;
        }
    }
#pragma unroll
    for (int h = 0; h < 4; ++h)
        *(float4*)&red[((g * 4 + h) << 7) + c * 4] = a[h];
    __syncthreads();
    for (int i = tid; i < 512; i += 256) {
        int h = i >> 7, dd = i & 127;
        float ssum = 0.f;
#pragma unroll
        for (int g2 = 0; g2 < 8; ++g2) ssum += red[((g2 * 4 + h) << 7) + dd];
        ctx[(h * Bb + b) * EPROJS_ + d0 + dd] = ssum;
    }
}

// ---------------- c[h,b,e] = sum_d ctx[h,b,d] * Wv[h,d,e] ---------------------
__global__ __launch_bounds__(256) void c_kernel(
    const float* __restrict__ ctx, const float* __restrict__ Wv,
    float* __restrict__ c_buf)
{
    int e = blockIdx.x * 256 + threadIdx.x;
    int d0 = blockIdx.y * 128;
    int h = blockIdx.z;
    float acc[32];
#pragma unroll
    for (int b = 0; b < 32; ++b) acc[b] = 0.f;
    for (int d = d0; d < d0 + 128; ++d) {
        float wv = Wv[(h * EPROJS_ + d) * DVd + e];
#pragma unroll
        for (int b = 0; b < 32; ++b) acc[b] += ctx[(h * Bb + b) * EPROJS_ + d] * wv;
    }
#pragma unroll
    for (int b = 0; b < 32; ++b)
        atomicAdd(&c_buf[(h * Bb + b) * DVd + e], acc[b]);
}

// ---------------- out[b,o] = sum_{h,e} c[h,b,e] * Wo[h*512+e, o] --------------
__global__ __launch_bounds__(256) void out_kernel(
    const float* __restrict__ c_buf, const float* __restrict__ Wo,
    float* __restrict__ outp)
{
    int o = blockIdx.x * 256 + threadIdx.x;
    int k0 = blockIdx.y * 256;
    float acc[32];
#pragma unroll
    for (int b = 0; b < 32; ++b) acc[b] = 0.f;
    for (int k = k0; k < k0 + 256; ++k) {
        int h = k >> 9, e = k & 511;
        float wo = Wo[(size_t)k * EPROJS_ + o];
#pragma unroll
        for (int b = 0; b < 32; ++b) acc[b] += c_buf[(h * Bb + b) * DVd + e] * wo;
    }
#pragma unroll
    for (int b = 0; b < 32; ++b)
        atomicAdd(&outp[b * EPROJS_ + o], acc[b]);
}

extern "C" void kernel_launch(void* const* d_in, const int* in_sizes, int n_in,
                              void* d_out, int out_size, void* d_ws, size_t ws_size,
                              hipStream_t stream) {
    const float* enc     = (const float*)d_in[0];
    const float* dec_z   = (const float*)d_in[2];
    const float* att_prev= (const float*)d_in[3];
    const float* Wq      = (const float*)d_in[4];
    const float* bq      = (const float*)d_in[5];
    const float* Wk      = (const float*)d_in[6];
    const float* Wv      = (const float*)d_in[7];
    const float* g_w     = (const float*)d_in[8];
    const float* Watt    = (const float*)d_in[10];
    const float* Wo      = (const float*)d_in[11];
    const float* cw0     = (const float*)d_in[12];
    const float* cw1     = (const float*)d_in[13];
    const float* cw2     = (const float*)d_in[14];
    const float* cw3     = (const float*)d_in[15];

    float* ws    = (float*)d_ws;
    float* q_buf = ws;                         // 65536 f
    float* e_buf = ws + 65536;                 // 128000 f
    float* c_buf = ws + 193536;                // 65536 f
    float* ctx   = ws + 259072;                // 131072 f
    __hip_bfloat16* Wkt = (__hip_bfloat16*)(ws + 390144);     // 2,097,152 bf16
    __hip_bfloat16* WWt = (__hip_bfloat16*)(ws + 1438720);    // 458,752 bf16
    float* outp  = (float*)d_out;              // 32768 f
    float* wout  = outp + 32768;               // 128000 f

    hipMemsetAsync(ws, 0, (size_t)259072 * sizeof(float), stream);
    hipMemsetAsync(d_out, 0, (size_t)32768 * sizeof(float), stream);

    wkt_kernel<<<dim3(16, 32, 4), 256, 0, stream>>>(Wk, Wkt);
    ww_kernel<<<dim3(2, 4, 7), 256, 0, stream>>>(cw0, cw1, cw2, cw3, Watt, WWt);
    q_kernel<<<dim3(2, 4, 4), 256, 0, stream>>>(dec_z, Wq, q_buf);
    e_kernel<<<dim3(4, 8, 128), 256, 0, stream>>>(enc, Wkt, att_prev, WWt,
                                                  q_buf, bq, g_w, e_buf);
    softmax_kernel<<<128, 256, 0, stream>>>(e_buf, wout);
    ctx_kernel<<<dim3(8, 32), 256, 0, stream>>>(wout, enc, ctx);
    c_kernel<<<dim3(2, 8, 4), 256, 0, stream>>>(ctx, Wv, c_buf);
    out_kernel<<<dim3(4, 8), 256, 0, stream>>>(c_buf, Wo, outp);
}

// Round 3
// 603.811 us; speedup vs baseline: 4.1069x; 1.8385x over previous
//
#include <hip/hip_runtime.h>
#include <hip/hip_bf16.h>
#include <math.h>

#define Hh 4
#define Bb 32
#define Tt 1000
#define TP 1024
#define EPROJS_ 1024
#define DUNITS_ 1024
#define DKd 512
#define DVd 512
#define CC 100
#define KPAD 224
#define SCALING 0.04419417382415922f  // 1/sqrt(512)

typedef __attribute__((ext_vector_type(8))) short short8;
typedef __attribute__((ext_vector_type(4))) float floatx4;

__device__ __forceinline__ void async16(const void* g, void* l) {
    __builtin_amdgcn_global_load_lds(
        (const __attribute__((address_space(1))) unsigned int*)g,
        (__attribute__((address_space(3))) unsigned int*)l, 16, 0, 0);
}

// ---------------- enc16[b][t][d] = bf16(enc[b][t][d]), t padded to 1024 --------
__global__ __launch_bounds__(256) void enc_cvt_kernel(
    const float* __restrict__ enc, unsigned short* __restrict__ enc16)
{
    int t = blockIdx.x, b = blockIdx.y;
    int d = threadIdx.x * 4;
    float4 v = *(const float4*)(enc + ((size_t)(b * Tt + t)) * EPROJS_ + d);
    union { __hip_bfloat162 h2[2]; uint2 u; } u;
    u.h2[0] = __float22bfloat162_rn(make_float2(v.x, v.y));
    u.h2[1] = __float22bfloat162_rn(make_float2(v.z, v.w));
    *(uint2*)(enc16 + ((size_t)(b * TP + t)) * EPROJS_ + d) = u.u;
}

// ---------------- Wkt[h][e][d] = bf16(Wk[h][d][e]) — 64x64 float4 transpose ----
__global__ __launch_bounds__(256) void wkt_kernel(
    const float* __restrict__ Wk, unsigned short* __restrict__ Wkt)
{
    int et = blockIdx.x;   // 0..7   (64-e tile)
    int dt = blockIdx.y;   // 0..15  (64-d tile)
    int h  = blockIdx.z;
    __shared__ float tile[64][65];
    int tid = threadIdx.x;
    int r = tid >> 4, c4 = tid & 15;
    const float* src = Wk + ((size_t)(h * DUNITS_ + dt * 64)) * DKd + et * 64;
#pragma unroll
    for (int rr = 0; rr < 4; ++rr) {
        int row = r + rr * 16;
        *(float4*)&tile[row][c4 * 4] = *(const float4*)(src + (size_t)row * DKd + c4 * 4);
    }
    __syncthreads();
    unsigned short* dst = Wkt + ((size_t)(h * DKd + et * 64)) * EPROJS_ + dt * 64;
#pragma unroll
    for (int rr = 0; rr < 4; ++rr) {
        int el = r + rr * 16;
        union { __hip_bfloat162 h2[2]; uint2 u; } u;
        u.h2[0] = __float22bfloat162_rn(make_float2(tile[c4 * 4 + 0][el], tile[c4 * 4 + 1][el]));
        u.h2[1] = __float22bfloat162_rn(make_float2(tile[c4 * 4 + 2][el], tile[c4 * 4 + 3][el]));
        *(uint2*)(dst + (size_t)el * EPROJS_ + c4 * 4) = u.u;
    }
}

// ------- WWt[h][e][k] = bf16(sum_c cw_h[c,k]*Watt[h,c,e]), k zero-padded to 224
__global__ __launch_bounds__(256) void ww_kernel(
    const float* __restrict__ w0, const float* __restrict__ w1,
    const float* __restrict__ w2, const float* __restrict__ w3,
    const float* __restrict__ Watt, __hip_bfloat16* __restrict__ WWt)
{
    int k = blockIdx.x;           // 0..223
    int h = blockIdx.y;
    int f = 25 * (h + 1), Kh = 2 * f + 1;
    const float* cw = (h == 0) ? w0 : (h == 1) ? w1 : (h == 2) ? w2 : w3;
    int e = threadIdx.x;
    float acc0 = 0.f, acc1 = 0.f;
    if (k < Kh) {
        for (int c = 0; c < CC; ++c) {
            float wv = cw[c * Kh + k];
            acc0 += wv * Watt[(h * CC + c) * DKd + e];
            acc1 += wv * Watt[(h * CC + c) * DKd + e + 256];
        }
    }
    WWt[((size_t)(h * DKd + e)) * KPAD + k] = __float2bfloat16(acc0);
    WWt[((size_t)(h * DKd + e + 256)) * KPAD + k] = __float2bfloat16(acc1);
}

// ---------------- q[h,b,e] += dec_z[b,d0:d0+64] . Wq[h,d0:d0+64,e] ------------
__global__ __launch_bounds__(256) void q_kernel(
    const float* __restrict__ dec_z, const float* __restrict__ Wq,
    float* __restrict__ q_buf)
{
    int et = blockIdx.x, kc = blockIdx.y, h = blockIdx.z;
    int d0 = kc * 64;
    __shared__ float zs[32][64];
    int tid = threadIdx.x;
    {
        int b = tid >> 3, dc = (tid & 7) * 8;
        const float* p = dec_z + (size_t)b * DUNITS_ + d0 + dc;
        *(float4*)&zs[b][dc] = *(const float4*)p;
        *(float4*)&zs[b][dc + 4] = *(const float4*)(p + 4);
    }
    __syncthreads();
    int e = et * 128 + (tid & 127);
    int dl0 = (tid >> 7) * 32;
    float wq[32];
#pragma unroll
    for (int dl = 0; dl < 32; ++dl)
        wq[dl] = Wq[((size_t)(h * DUNITS_ + d0 + dl0 + dl)) * DKd + e];
#pragma unroll
    for (int b = 0; b < 32; ++b) {
        float s = 0.f;
#pragma unroll
        for (int dl = 0; dl < 32; ++dl) s += zs[b][dl0 + dl] * wq[dl];
        atomicAdd(&q_buf[(h * Bb + b) * DKd + e], s);
    }
}

// ---------------- e[h,b,t]: MFMA bf16 GEMM + fused tanh-dot epilogue -----------
__global__ __launch_bounds__(256) void e_kernel(
    const unsigned short* __restrict__ enc16, const unsigned short* __restrict__ Wkt,
    const float* __restrict__ att_prev, const __hip_bfloat16* __restrict__ WWt,
    const float* __restrict__ q_buf, const float* __restrict__ bq,
    const float* __restrict__ g_w, float* __restrict__ e_buf)
{
    const int bx = blockIdx.x;   // e0 block 0..3
    const int by = blockIdx.y;   // t tile 0..7
    const int bz = blockIdx.z;   // h*32+b
    const int h = bz >> 5, b = bz & 31;
    const int t0 = by * 128, e0 = bx * 128;
    const int tid = threadIdx.x;
    const int lane = tid & 63, w = tid >> 6;
    const int wr = w >> 1, wc = w & 1;
    const int m = lane & 15, quad = lane >> 4;
    const int rr = tid >> 2, ko = (tid & 3) * 8;  // staging row / 16B slot

    __shared__ __align__(16) short As[128 * 32];
    __shared__ __align__(16) short Bs[128 * 32];

    floatx4 acc[4][4];
#pragma unroll
    for (int i = 0; i < 4; ++i)
#pragma unroll
        for (int j = 0; j < 4; ++j) acc[i][j] = (floatx4){0.f, 0.f, 0.f, 0.f};

    const unsigned short* WkB = Wkt + ((size_t)(h * DKd + e0)) * EPROJS_;
    const unsigned short* encB = enc16 + ((size_t)(b * TP + t0)) * EPROJS_;
    char* AsDst = (char*)As + (tid & ~63) * 16;   // wave-uniform base
    char* BsDst = (char*)Bs + (tid & ~63) * 16;

    // ---- phase 1: K=1024 over d, BK=32, both operands via global_load_lds ----
    for (int ch = 0; ch < 32; ++ch) {
        int d0 = ch * 32;
        __syncthreads();   // prior ds_reads done before overwrite
#pragma unroll
        for (int it = 0; it < 2; ++it) {
            int r2 = rr + it * 64;
            async16(encB + (size_t)r2 * EPROJS_ + d0 + ko, AsDst + it * 4096);
            async16(WkB + (size_t)r2 * EPROJS_ + d0 + ko, BsDst + it * 4096);
        }
        __syncthreads();   // drains vmcnt before use
        short8 af[4], bf[4];
#pragma unroll
        for (int i = 0; i < 4; ++i)
            af[i] = *(const short8*)&As[(wr * 64 + i * 16 + m) * 32 + quad * 8];
#pragma unroll
        for (int j = 0; j < 4; ++j)
            bf[j] = *(const short8*)&Bs[(wc * 64 + j * 16 + m) * 32 + quad * 8];
#pragma unroll
        for (int i = 0; i < 4; ++i)
#pragma unroll
            for (int j = 0; j < 4; ++j)
                acc[i][j] = __builtin_amdgcn_mfma_f32_16x16x32_bf16(
                    af[i], bf[j], acc[i][j], 0, 0, 0);
    }

    // ---- phase 2: banded location term over k, BK=32 ----
    const int f = 25 * (h + 1);
    const int Kh = 2 * f + 1;
    const int nch2 = (Kh + 31) >> 5;
    const float* ab = att_prev + (size_t)(h * Bb + b) * Tt;
    const __hip_bfloat16* WWB = WWt + ((size_t)(h * DKd + e0)) * KPAD;
    for (int ch = 0; ch < nch2; ++ch) {
        int k0 = ch * 32;
        int ar = tid >> 1, kh = (tid & 1) * 16;
        int sbase = t0 + ar - f + k0 + kh;
        float v[16];
#pragma unroll
        for (int j2 = 0; j2 < 16; ++j2) {
            int s = sbase + j2;
            v[j2] = (s >= 0 && s < Tt) ? ab[s] : 0.f;
        }
        __syncthreads();
#pragma unroll
        for (int it = 0; it < 2; ++it) {
            int r2 = rr + it * 64;
            async16(WWB + (size_t)r2 * KPAD + k0 + ko, BsDst + it * 4096);
        }
        union { short8 s[2]; __hip_bfloat162 hh[8]; } u;
#pragma unroll
        for (int j2 = 0; j2 < 8; ++j2)
            u.hh[j2] = __float22bfloat162_rn(make_float2(v[2 * j2], v[2 * j2 + 1]));
        *(short8*)&As[ar * 32 + kh] = u.s[0];
        *(short8*)&As[ar * 32 + kh + 8] = u.s[1];
        __syncthreads();
        short8 af[4], bf[4];
#pragma unroll
        for (int i = 0; i < 4; ++i)
            af[i] = *(const short8*)&As[(wr * 64 + i * 16 + m) * 32 + quad * 8];
#pragma unroll
        for (int j = 0; j < 4; ++j)
            bf[j] = *(const short8*)&Bs[(wc * 64 + j * 16 + m) * 32 + quad * 8];
#pragma unroll
        for (int i = 0; i < 4; ++i)
#pragma unroll
            for (int j = 0; j < 4; ++j)
                acc[i][j] = __builtin_amdgcn_mfma_f32_16x16x32_bf16(
                    af[i], bf[j], acc[i][j], 0, 0, 0);
    }

    // ---- epilogue: +q+bq, tanh, *g_w, reduce 16 cols/quad, atomicAdd ----------
    const float* qrow = q_buf + (size_t)(h * Bb + b) * DKd;
    const float* bqrow = bq + h * DKd;
    const float* gwrow = g_w + h * DKd;
    float qv[4], gw[4];
#pragma unroll
    for (int j = 0; j < 4; ++j) {
        int e = e0 + wc * 64 + j * 16 + m;
        qv[j] = qrow[e] + bqrow[e];
        gw[j] = gwrow[e];
    }
    float* erow = e_buf + (size_t)(h * Bb + b) * Tt;
#pragma unroll
    for (int i = 0; i < 4; ++i) {
#pragma unroll
        for (int reg = 0; reg < 4; ++reg) {
            float s = 0.f;
#pragma unroll
            for (int j = 0; j < 4; ++j)
                s += tanhf(acc[i][j][reg] + qv[j]) * gw[j];
            s += __shfl_xor(s, 1);
            s += __shfl_xor(s, 2);
            s += __shfl_xor(s, 4);
            s += __shfl_xor(s, 8);
            int t = t0 + wr * 64 + i * 16 + quad * 4 + reg;
            if (m == 0 && t < Tt)
                atomicAdd(&erow[t], s);
        }
    }
}

// ---------------- w = softmax(scaling * e) over T ------------------------------
__global__ __launch_bounds__(256) void softmax_kernel(
    const float* __restrict__ e_buf, float* __restrict__ wout)
{
    int rowid = blockIdx.x;
    const float* x = e_buf + rowid * Tt;
    float* y = wout + rowid * Tt;
    int tid = threadIdx.x;
    float v[4];
    float mx = -1e30f;
#pragma unroll
    for (int k = 0; k < 4; ++k) {
        int t = tid + k * 256;
        v[k] = (t < Tt) ? x[t] * SCALING : -1e30f;
        mx = fmaxf(mx, v[k]);
    }
    for (int off = 32; off >= 1; off >>= 1) mx = fmaxf(mx, __shfl_xor(mx, off));
    __shared__ float sm[4];
    __shared__ float ss[4];
    int wave = tid >> 6;
    if ((tid & 63) == 0) sm[wave] = mx;
    __syncthreads();
    mx = fmaxf(fmaxf(sm[0], sm[1]), fmaxf(sm[2], sm[3]));
    float s = 0.f;
#pragma unroll
    for (int k = 0; k < 4; ++k) {
        int t = tid + k * 256;
        v[k] = (t < Tt) ? __expf(v[k] - mx) : 0.f;
        s += v[k];
    }
    for (int off = 32; off >= 1; off >>= 1) s += __shfl_xor(s, off);
    if ((tid & 63) == 0) ss[wave] = s;
    __syncthreads();
    s = ss[0] + ss[1] + ss[2] + ss[3];
    float inv = 1.0f / s;
#pragma unroll
    for (int k = 0; k < 4; ++k) {
        int t = tid + k * 256;
        if (t < Tt) y[t] = v[k] * inv;
    }
}

// ---------------- ctx[h,b,d] += sum_{t in tile} w[h,b,t] * enc[b,t,d] ---------
__global__ __launch_bounds__(256) void ctx_kernel(
    const float* __restrict__ wout, const float* __restrict__ enc,
    float* __restrict__ ctx)
{
    int dch = blockIdx.x;    // 0..7 : 128-d chunk
    int b = blockIdx.y;      // 0..31
    int tq = blockIdx.z;     // 0..3 : 250-t chunk
    int t0 = tq * 250;
    int tid = threadIdx.x;
    __shared__ float wl[4][252];
    __shared__ float red[8 * 4 * 128];
    for (int i = tid; i < 1000; i += 256) {
        int h = i / 250, tl = i - h * 250;
        wl[h][tl] = wout[(h * Bb + b) * Tt + t0 + tl];
    }
    __syncthreads();
    int g = tid >> 5, c = tid & 31;
    int d0 = dch * 128;
    float4 a[4];
#pragma unroll
    for (int h = 0; h < 4; ++h) a[h] = make_float4(0.f, 0.f, 0.f, 0.f);
    for (int t = t0 + g; t < t0 + 250; t += 8) {
        float4 ev = *(const float4*)(enc + ((size_t)(b * Tt + t)) * EPROJS_ + d0 + c * 4);
#pragma unroll
        for (int h = 0; h < 4; ++h) {
            float wv = wl[h][t - t0];
            a[h].x += wv * ev.x; a[h].y += wv * ev.y;
            a[h].z += wv * ev.z; a[h].w += wv * ev.w;
        }
    }
#pragma unroll
    for (int h = 0; h < 4; ++h)
        *(float4*)&red[((g * 4 + h) << 7) + c * 4] = a[h];
    __syncthreads();
    for (int i = tid; i < 512; i += 256) {
        int h = i >> 7, dd = i & 127;
        float ssum = 0.f;
#pragma unroll
        for (int g2 = 0; g2 < 8; ++g2) ssum += red[((g2 * 4 + h) << 7) + dd];
        atomicAdd(&ctx[(h * Bb + b) * EPROJS_ + d0 + dd], ssum);
    }
}

// ---------------- c[h,b,e] += ctx[h,b,d0:d0+64] . Wv[h,d0:d0+64,e] ------------
__global__ __launch_bounds__(256) void c_kernel(
    const float* __restrict__ ctx, const float* __restrict__ Wv,
    float* __restrict__ c_buf)
{
    int et = blockIdx.x, kc = blockIdx.y, h = blockIdx.z;
    int d0 = kc * 64;
    __shared__ float zs[32][64];
    int tid = threadIdx.x;
    {
        int b = tid >> 3, dc = (tid & 7) * 8;
        const float* p = ctx + ((size_t)(h * Bb + b)) * EPROJS_ + d0 + dc;
        *(float4*)&zs[b][dc] = *(const float4*)p;
        *(float4*)&zs[b][dc + 4] = *(const float4*)(p + 4);
    }
    __syncthreads();
    int e = et * 128 + (tid & 127);
    int dl0 = (tid >> 7) * 32;
    float wv[32];
#pragma unroll
    for (int dl = 0; dl < 32; ++dl)
        wv[dl] = Wv[((size_t)(h * EPROJS_ + d0 + dl0 + dl)) * DVd + e];
#pragma unroll
    for (int b = 0; b < 32; ++b) {
        float s = 0.f;
#pragma unroll
        for (int dl = 0; dl < 32; ++dl) s += zs[b][dl0 + dl] * wv[dl];
        atomicAdd(&c_buf[(h * Bb + b) * DVd + e], s);
    }
}

// ---------------- out[b,o] += c[b,k0:k0+64] . Wo[k0:k0+64,o] ------------------
__global__ __launch_bounds__(256) void out_kernel(
    const float* __restrict__ c_buf, const float* __restrict__ Wo,
    float* __restrict__ outp)
{
    int ot = blockIdx.x;  // 0..7 : 128-o tile
    int kc = blockIdx.y;  // 0..31: 64-k chunk
    int k0 = kc * 64, o0 = ot * 128;
    __shared__ float cs[32][64];
    int tid = threadIdx.x;
    {
        int b = tid >> 3, k8 = (tid & 7) * 8;
        int h = k0 >> 9;
        const float* p = c_buf + ((size_t)(h * Bb + b)) * DVd + (k0 & 511) + k8;
        *(float4*)&cs[b][k8] = *(const float4*)p;
        *(float4*)&cs[b][k8 + 4] = *(const float4*)(p + 4);
    }
    __syncthreads();
    int o = o0 + (tid & 127);
    int kl0 = (tid >> 7) * 32;
    float wo[32];
#pragma unroll
    for (int kl = 0; kl < 32; ++kl)
        wo[kl] = Wo[((size_t)(k0 + kl0 + kl)) * EPROJS_ + o];
#pragma unroll
    for (int b = 0; b < 32; ++b) {
        float s = 0.f;
#pragma unroll
        for (int kl = 0; kl < 32; ++kl) s += cs[b][kl0 + kl] * wo[kl];
        atomicAdd(&outp[b * EPROJS_ + o], s);
    }
}

extern "C" void kernel_launch(void* const* d_in, const int* in_sizes, int n_in,
                              void* d_out, int out_size, void* d_ws, size_t ws_size,
                              hipStream_t stream) {
    const float* enc     = (const float*)d_in[0];
    const float* dec_z   = (const float*)d_in[2];
    const float* att_prev= (const float*)d_in[3];
    const float* Wq      = (const float*)d_in[4];
    const float* bq      = (const float*)d_in[5];
    const float* Wk      = (const float*)d_in[6];
    const float* Wv      = (const float*)d_in[7];
    const float* g_w     = (const float*)d_in[8];
    const float* Watt    = (const float*)d_in[10];
    const float* Wo      = (const float*)d_in[11];
    const float* cw0     = (const float*)d_in[12];
    const float* cw1     = (const float*)d_in[13];
    const float* cw2     = (const float*)d_in[14];
    const float* cw3     = (const float*)d_in[15];

    float* ws    = (float*)d_ws;
    float* q_buf = ws;                          // 65536 f
    float* e_buf = ws + 65536;                  // 128000 f
    float* c_buf = ws + 193536;                 // 65536 f
    float* ctx   = ws + 259072;                 // 131072 f   (zeroed through here)
    unsigned short* enc16 = (unsigned short*)(ws + 390144);   // 32*1024*1024 bf16
    unsigned short* Wkt   = (unsigned short*)(ws + 17167360); // 4*512*1024 bf16
    __hip_bfloat16* WWt   = (__hip_bfloat16*)(ws + 18215936); // 4*512*224 bf16
    float* outp  = (float*)d_out;               // 32768 f
    float* wout  = outp + 32768;                // 128000 f

    // zero atomic-accumulated buffers: q, e, c, ctx, out
    hipMemsetAsync(ws, 0, (size_t)390144 * sizeof(float), stream);
    hipMemsetAsync(d_out, 0, (size_t)32768 * sizeof(float), stream);

    enc_cvt_kernel<<<dim3(Tt, Bb), 256, 0, stream>>>(enc, enc16);
    wkt_kernel<<<dim3(8, 16, 4), 256, 0, stream>>>(Wk, Wkt);
    ww_kernel<<<dim3(KPAD, 4), 256, 0, stream>>>(cw0, cw1, cw2, cw3, Watt, WWt);
    q_kernel<<<dim3(4, 16, 4), 256, 0, stream>>>(dec_z, Wq, q_buf);
    e_kernel<<<dim3(4, 8, 128), 256, 0, stream>>>(enc16, Wkt, att_prev, WWt,
                                                  q_buf, bq, g_w, e_buf);
    softmax_kernel<<<128, 256, 0, stream>>>(e_buf, wout);
    ctx_kernel<<<dim3(8, 32, 4), 256, 0, stream>>>(wout, enc, ctx);
    c_kernel<<<dim3(4, 16, 4), 256, 0, stream>>>(ctx, Wv, c_buf);
    out_kernel<<<dim3(8, 32), 256, 0, stream>>>(c_buf, Wo, outp);
}

// Round 4
// 568.343 us; speedup vs baseline: 4.3632x; 1.0624x over previous
//
#include <hip/hip_runtime.h>
#include <hip/hip_bf16.h>
#include <math.h>

#define Hh 4
#define Bb 32
#define Tt 1000
#define TP 1024
#define EPROJS_ 1024
#define DUNITS_ 1024
#define DKd 512
#define DVd 512
#define CC 100
#define KPAD 256
#define SCALING 0.04419417382415922f  // 1/sqrt(512)

typedef __attribute__((ext_vector_type(8))) short short8;
typedef __attribute__((ext_vector_type(4))) float floatx4;

__device__ __forceinline__ void async16(const void* g, void* l) {
    __builtin_amdgcn_global_load_lds(
        (const __attribute__((address_space(1))) unsigned int*)g,
        (__attribute__((address_space(3))) unsigned int*)l, 16, 0, 0);
}

// ---------------- enc16[b][t][d] = bf16(enc[b][t][d]), t padded to 1024 --------
__global__ __launch_bounds__(256) void enc_cvt_kernel(
    const float* __restrict__ enc, unsigned short* __restrict__ enc16)
{
    int t = blockIdx.x, b = blockIdx.y;
    int d = threadIdx.x * 4;
    float4 v = *(const float4*)(enc + ((size_t)(b * Tt + t)) * EPROJS_ + d);
    union { __hip_bfloat162 h2[2]; uint2 u; } u;
    u.h2[0] = __float22bfloat162_rn(make_float2(v.x, v.y));
    u.h2[1] = __float22bfloat162_rn(make_float2(v.z, v.w));
    *(uint2*)(enc16 + ((size_t)(b * TP + t)) * EPROJS_ + d) = u.u;
}

// ---------------- Wkt[h][e][d] = bf16(Wk[h][d][e]) — 64x64 float4 transpose ----
__global__ __launch_bounds__(256) void wkt_kernel(
    const float* __restrict__ Wk, unsigned short* __restrict__ Wkt)
{
    int et = blockIdx.x;   // 0..7
    int dt = blockIdx.y;   // 0..15
    int h  = blockIdx.z;
    __shared__ float tile[64][65];
    int tid = threadIdx.x;
    int r = tid >> 4, c4 = tid & 15;
    const float* src = Wk + ((size_t)(h * DUNITS_ + dt * 64)) * DKd + et * 64;
#pragma unroll
    for (int rr = 0; rr < 4; ++rr) {
        int row = r + rr * 16;
        *(float4*)&tile[row][c4 * 4] = *(const float4*)(src + (size_t)row * DKd + c4 * 4);
    }
    __syncthreads();
    unsigned short* dst = Wkt + ((size_t)(h * DKd + et * 64)) * EPROJS_ + dt * 64;
#pragma unroll
    for (int rr = 0; rr < 4; ++rr) {
        int el = r + rr * 16;
        union { __hip_bfloat162 h2[2]; uint2 u; } u;
        u.h2[0] = __float22bfloat162_rn(make_float2(tile[c4 * 4 + 0][el], tile[c4 * 4 + 1][el]));
        u.h2[1] = __float22bfloat162_rn(make_float2(tile[c4 * 4 + 2][el], tile[c4 * 4 + 3][el]));
        *(uint2*)(dst + (size_t)el * EPROJS_ + c4 * 4) = u.u;
    }
}

// ------- WWt[h][e][k] = bf16(sum_c cw_h[c,k]*Watt[h,c,e]), k zero-padded to 256
__global__ __launch_bounds__(256) void ww_kernel(
    const float* __restrict__ w0, const float* __restrict__ w1,
    const float* __restrict__ w2, const float* __restrict__ w3,
    const float* __restrict__ Watt, __hip_bfloat16* __restrict__ WWt)
{
    int k = blockIdx.x;           // 0..255
    int h = blockIdx.y;
    int f = 25 * (h + 1), Kh = 2 * f + 1;
    const float* cw = (h == 0) ? w0 : (h == 1) ? w1 : (h == 2) ? w2 : w3;
    int e = threadIdx.x;
    float acc0 = 0.f, acc1 = 0.f;
    if (k < Kh) {
        for (int c = 0; c < CC; ++c) {
            float wv = cw[c * Kh + k];
            acc0 += wv * Watt[(h * CC + c) * DKd + e];
            acc1 += wv * Watt[(h * CC + c) * DKd + e + 256];
        }
    }
    WWt[((size_t)(h * DKd + e)) * KPAD + k] = __float2bfloat16(acc0);
    WWt[((size_t)(h * DKd + e + 256)) * KPAD + k] = __float2bfloat16(acc1);
}

// ---------------- q[h,b,e] += dec_z[b,d0:d0+64] . Wq[h,d0:d0+64,e] ------------
__global__ __launch_bounds__(256) void q_kernel(
    const float* __restrict__ dec_z, const float* __restrict__ Wq,
    float* __restrict__ q_buf)
{
    int et = blockIdx.x, kc = blockIdx.y, h = blockIdx.z;
    int d0 = kc * 64;
    __shared__ float zs[32][64];
    int tid = threadIdx.x;
    {
        int b = tid >> 3, dc = (tid & 7) * 8;
        const float* p = dec_z + (size_t)b * DUNITS_ + d0 + dc;
        *(float4*)&zs[b][dc] = *(const float4*)p;
        *(float4*)&zs[b][dc + 4] = *(const float4*)(p + 4);
    }
    __syncthreads();
    int e = et * 128 + (tid & 127);
    int dl0 = (tid >> 7) * 32;
    float wq[32];
#pragma unroll
    for (int dl = 0; dl < 32; ++dl)
        wq[dl] = Wq[((size_t)(h * DUNITS_ + d0 + dl0 + dl)) * DKd + e];
#pragma unroll
    for (int b = 0; b < 32; ++b) {
        float s = 0.f;
#pragma unroll
        for (int dl = 0; dl < 32; ++dl) s += zs[b][dl0 + dl] * wq[dl];
        atomicAdd(&q_buf[(h * Bb + b) * DKd + e], s);
    }
}

// ---------------- e[h,b,t]: MFMA bf16 GEMM + fused tanh-dot epilogue -----------
// 1D grid, XCD-aware: b = (lin&7) + 8*(pos>>7) so all blocks of batch b share
// one XCD's L2. BK=64, XOR-swizzled LDS (phys slot = log slot ^ (row&7)).
__global__ __launch_bounds__(256) void e_kernel(
    const unsigned short* __restrict__ enc16, const unsigned short* __restrict__ Wkt,
    const float* __restrict__ att_prev, const __hip_bfloat16* __restrict__ WWt,
    const float* __restrict__ q_buf, const float* __restrict__ bq,
    const float* __restrict__ g_w, float* __restrict__ e_buf)
{
    const int lin = blockIdx.x;
    const int xcd = lin & 7, pos = lin >> 3;
    const int b = (pos >> 7) * 8 + xcd;
    const int rem = pos & 127;
    const int h = rem >> 5;
    const int by = (rem & 31) >> 2;
    const int bx = rem & 3;
    const int t0 = by * 128, e0 = bx * 128;
    const int tid = threadIdx.x;
    const int lane = tid & 63, w = tid >> 6;
    const int wr = w >> 1, wc = w & 1;
    const int m = lane & 15, quad = lane >> 4;
    // staging: thread covers row r = it*32 + (tid>>3), 16B slot (swizzled source)
    const int srow = tid >> 3;
    const int ko = (((tid & 7) ^ (srow & 7))) * 8;   // swizzled k-offset (elements)
    const int sw = m & 7;                             // fragment-read swizzle

    __shared__ __align__(16) short As[128 * 64];
    __shared__ __align__(16) short Bs[128 * 64];

    floatx4 acc[4][4];
#pragma unroll
    for (int i = 0; i < 4; ++i)
#pragma unroll
        for (int j = 0; j < 4; ++j) acc[i][j] = (floatx4){0.f, 0.f, 0.f, 0.f};

    const unsigned short* WkB = Wkt + ((size_t)(h * DKd + e0)) * EPROJS_;
    const unsigned short* encB = enc16 + ((size_t)(b * TP + t0)) * EPROJS_;
    char* AsDst = (char*)As + (tid & ~63) * 16;   // wave-uniform base
    char* BsDst = (char*)Bs + (tid & ~63) * 16;

    // ---- phase 1: K=1024 over d, BK=64, both operands via global_load_lds ----
    for (int ch = 0; ch < 16; ++ch) {
        int d0 = ch * 64;
        __syncthreads();   // prior ds_reads done before overwrite
#pragma unroll
        for (int it = 0; it < 4; ++it) {
            int r2 = it * 32 + srow;
            async16(encB + (size_t)r2 * EPROJS_ + d0 + ko, AsDst + it * 4096);
            async16(WkB + (size_t)r2 * EPROJS_ + d0 + ko, BsDst + it * 4096);
        }
        __syncthreads();   // drains vmcnt before use
#pragma unroll
        for (int ks = 0; ks < 2; ++ks) {
            short8 af[4], bf[4];
#pragma unroll
            for (int i = 0; i < 4; ++i)
                af[i] = *(const short8*)&As[(wr * 64 + i * 16 + m) * 64 + (((ks << 2) + quad) ^ sw) * 8];
#pragma unroll
            for (int j = 0; j < 4; ++j)
                bf[j] = *(const short8*)&Bs[(wc * 64 + j * 16 + m) * 64 + (((ks << 2) + quad) ^ sw) * 8];
#pragma unroll
            for (int i = 0; i < 4; ++i)
#pragma unroll
                for (int j = 0; j < 4; ++j)
                    acc[i][j] = __builtin_amdgcn_mfma_f32_16x16x32_bf16(
                        af[i], bf[j], acc[i][j], 0, 0, 0);
        }
    }

    // ---- phase 2: banded location term over k, BK=64 ----
    const int f = 25 * (h + 1);
    const int Kh = 2 * f + 1;
    const int nch2 = (Kh + 63) >> 6;
    const float* ab = att_prev + (size_t)(h * Bb + b) * Tt;
    const __hip_bfloat16* WWB = WWt + ((size_t)(h * DKd + e0)) * KPAD;
    for (int ch = 0; ch < nch2; ++ch) {
        int k0 = ch * 64;
        int ar = tid >> 1, half = tid & 1;
        int sbase = t0 + ar - f + k0 + half * 32;
        float v[32];
#pragma unroll
        for (int j2 = 0; j2 < 32; ++j2) {
            int s = sbase + j2;
            v[j2] = (s >= 0 && s < Tt) ? ab[s] : 0.f;
        }
        __syncthreads();
#pragma unroll
        for (int it = 0; it < 4; ++it) {
            int r2 = it * 32 + srow;
            async16(WWB + (size_t)r2 * KPAD + k0 + ko, BsDst + it * 4096);
        }
        union { short8 s[4]; __hip_bfloat162 hh[16]; } u;
#pragma unroll
        for (int j2 = 0; j2 < 16; ++j2)
            u.hh[j2] = __float22bfloat162_rn(make_float2(v[2 * j2], v[2 * j2 + 1]));
#pragma unroll
        for (int jj = 0; jj < 4; ++jj) {
            int phys = (half * 4 + jj) ^ (ar & 7);
            *(short8*)&As[ar * 64 + phys * 8] = u.s[jj];
        }
        __syncthreads();
#pragma unroll
        for (int ks = 0; ks < 2; ++ks) {
            short8 af[4], bf[4];
#pragma unroll
            for (int i = 0; i < 4; ++i)
                af[i] = *(const short8*)&As[(wr * 64 + i * 16 + m) * 64 + (((ks << 2) + quad) ^ sw) * 8];
#pragma unroll
            for (int j = 0; j < 4; ++j)
                bf[j] = *(const short8*)&Bs[(wc * 64 + j * 16 + m) * 64 + (((ks << 2) + quad) ^ sw) * 8];
#pragma unroll
            for (int i = 0; i < 4; ++i)
#pragma unroll
                for (int j = 0; j < 4; ++j)
                    acc[i][j] = __builtin_amdgcn_mfma_f32_16x16x32_bf16(
                        af[i], bf[j], acc[i][j], 0, 0, 0);
        }
    }

    // ---- epilogue: +q+bq, tanh, *g_w, reduce 16 cols/quad, atomicAdd ----------
    const float* qrow = q_buf + (size_t)(h * Bb + b) * DKd;
    const float* bqrow = bq + h * DKd;
    const float* gwrow = g_w + h * DKd;
    float qv[4], gw[4];
#pragma unroll
    for (int j = 0; j < 4; ++j) {
        int e = e0 + wc * 64 + j * 16 + m;
        qv[j] = qrow[e] + bqrow[e];
        gw[j] = gwrow[e];
    }
    float* erow = e_buf + (size_t)(h * Bb + b) * Tt;
#pragma unroll
    for (int i = 0; i < 4; ++i) {
#pragma unroll
        for (int reg = 0; reg < 4; ++reg) {
            float s = 0.f;
#pragma unroll
            for (int j = 0; j < 4; ++j)
                s += tanhf(acc[i][j][reg] + qv[j]) * gw[j];
            s += __shfl_xor(s, 1);
            s += __shfl_xor(s, 2);
            s += __shfl_xor(s, 4);
            s += __shfl_xor(s, 8);
            int t = t0 + wr * 64 + i * 16 + quad * 4 + reg;
            if (m == 0 && t < Tt)
                atomicAdd(&erow[t], s);
        }
    }
}

// ---------------- w = softmax(scaling * e) over T ------------------------------
__global__ __launch_bounds__(256) void softmax_kernel(
    const float* __restrict__ e_buf, float* __restrict__ wout)
{
    int rowid = blockIdx.x;
    const float* x = e_buf + rowid * Tt;
    float* y = wout + rowid * Tt;
    int tid = threadIdx.x;
    float v[4];
    float mx = -1e30f;
#pragma unroll
    for (int k = 0; k < 4; ++k) {
        int t = tid + k * 256;
        v[k] = (t < Tt) ? x[t] * SCALING : -1e30f;
        mx = fmaxf(mx, v[k]);
    }
    for (int off = 32; off >= 1; off >>= 1) mx = fmaxf(mx, __shfl_xor(mx, off));
    __shared__ float sm[4];
    __shared__ float ss[4];
    int wave = tid >> 6;
    if ((tid & 63) == 0) sm[wave] = mx;
    __syncthreads();
    mx = fmaxf(fmaxf(sm[0], sm[1]), fmaxf(sm[2], sm[3]));
    float s = 0.f;
#pragma unroll
    for (int k = 0; k < 4; ++k) {
        int t = tid + k * 256;
        v[k] = (t < Tt) ? __expf(v[k] - mx) : 0.f;
        s += v[k];
    }
    for (int off = 32; off >= 1; off >>= 1) s += __shfl_xor(s, off);
    if ((tid & 63) == 0) ss[wave] = s;
    __syncthreads();
    s = ss[0] + ss[1] + ss[2] + ss[3];
    float inv = 1.0f / s;
#pragma unroll
    for (int k = 0; k < 4; ++k) {
        int t = tid + k * 256;
        if (t < Tt) y[t] = v[k] * inv;
    }
}

// ---------------- ctx[h,b,d] += sum_{t in tile} w[h,b,t] * enc16[b,t,d] -------
__global__ __launch_bounds__(256) void ctx_kernel(
    const float* __restrict__ wout, const unsigned short* __restrict__ enc16,
    float* __restrict__ ctx)
{
    int dch = blockIdx.x;    // 0..7 : 128-d chunk
    int b = blockIdx.y;      // 0..31
    int tq = blockIdx.z;     // 0..3 : 250-t chunk
    int t0 = tq * 250;
    int tid = threadIdx.x;
    __shared__ float wl[4][252];
    __shared__ float red[8 * 4 * 128];
    for (int i = tid; i < 1000; i += 256) {
        int h = i / 250, tl = i - h * 250;
        wl[h][tl] = wout[(h * Bb + b) * Tt + t0 + tl];
    }
    __syncthreads();
    int g = tid >> 5, c = tid & 31;
    int d0 = dch * 128;
    float4 a[4];
#pragma unroll
    for (int h = 0; h < 4; ++h) a[h] = make_float4(0.f, 0.f, 0.f, 0.f);
    const unsigned short* encB = enc16 + (size_t)b * TP * EPROJS_ + d0 + c * 4;
    for (int t = t0 + g; t < t0 + 250; t += 8) {
        uint2 raw = *(const uint2*)(encB + (size_t)t * EPROJS_);
        float x0 = __uint_as_float(raw.x << 16);
        float x1 = __uint_as_float(raw.x & 0xffff0000u);
        float x2 = __uint_as_float(raw.y << 16);
        float x3 = __uint_as_float(raw.y & 0xffff0000u);
#pragma unroll
        for (int h = 0; h < 4; ++h) {
            float wv = wl[h][t - t0];
            a[h].x += wv * x0; a[h].y += wv * x1;
            a[h].z += wv * x2; a[h].w += wv * x3;
        }
    }
#pragma unroll
    for (int h = 0; h < 4; ++h)
        *(float4*)&red[((g * 4 + h) << 7) + c * 4] = a[h];
    __syncthreads();
    for (int i = tid; i < 512; i += 256) {
        int h = i >> 7, dd = i & 127;
        float ssum = 0.f;
#pragma unroll
        for (int g2 = 0; g2 < 8; ++g2) ssum += red[((g2 * 4 + h) << 7) + dd];
        atomicAdd(&ctx[(h * Bb + b) * EPROJS_ + d0 + dd], ssum);
    }
}

// ---------------- c[h,b,e] += ctx[h,b,d0:d0+64] . Wv[h,d0:d0+64,e] ------------
__global__ __launch_bounds__(256) void c_kernel(
    const float* __restrict__ ctx, const float* __restrict__ Wv,
    float* __restrict__ c_buf)
{
    int et = blockIdx.x, kc = blockIdx.y, h = blockIdx.z;
    int d0 = kc * 64;
    __shared__ float zs[32][64];
    int tid = threadIdx.x;
    {
        int b = tid >> 3, dc = (tid & 7) * 8;
        const float* p = ctx + ((size_t)(h * Bb + b)) * EPROJS_ + d0 + dc;
        *(float4*)&zs[b][dc] = *(const float4*)p;
        *(float4*)&zs[b][dc + 4] = *(const float4*)(p + 4);
    }
    __syncthreads();
    int e = et * 128 + (tid & 127);
    int dl0 = (tid >> 7) * 32;
    float wv[32];
#pragma unroll
    for (int dl = 0; dl < 32; ++dl)
        wv[dl] = Wv[((size_t)(h * EPROJS_ + d0 + dl0 + dl)) * DVd + e];
#pragma unroll
    for (int b = 0; b < 32; ++b) {
        float s = 0.f;
#pragma unroll
        for (int dl = 0; dl < 32; ++dl) s += zs[b][dl0 + dl] * wv[dl];
        atomicAdd(&c_buf[(h * Bb + b) * DVd + e], s);
    }
}

// ---------------- out[b,o] += c[b,k0:k0+64] . Wo[k0:k0+64,o] ------------------
__global__ __launch_bounds__(256) void out_kernel(
    const float* __restrict__ c_buf, const float* __restrict__ Wo,
    float* __restrict__ outp)
{
    int ot = blockIdx.x;  // 0..7 : 128-o tile
    int kc = blockIdx.y;  // 0..31: 64-k chunk
    int k0 = kc * 64, o0 = ot * 128;
    __shared__ float cs[32][64];
    int tid = threadIdx.x;
    {
        int b = tid >> 3, k8 = (tid & 7) * 8;
        int h = k0 >> 9;
        const float* p = c_buf + ((size_t)(h * Bb + b)) * DVd + (k0 & 511) + k8;
        *(float4*)&cs[b][k8] = *(const float4*)p;
        *(float4*)&cs[b][k8 + 4] = *(const float4*)(p + 4);
    }
    __syncthreads();
    int o = o0 + (tid & 127);
    int kl0 = (tid >> 7) * 32;
    float wo[32];
#pragma unroll
    for (int kl = 0; kl < 32; ++kl)
        wo[kl] = Wo[((size_t)(k0 + kl0 + kl)) * EPROJS_ + o];
#pragma unroll
    for (int b = 0; b < 32; ++b) {
        float s = 0.f;
#pragma unroll
        for (int kl = 0; kl < 32; ++kl) s += cs[b][kl0 + kl] * wo[kl];
        atomicAdd(&outp[b * EPROJS_ + o], s);
    }
}

extern "C" void kernel_launch(void* const* d_in, const int* in_sizes, int n_in,
                              void* d_out, int out_size, void* d_ws, size_t ws_size,
                              hipStream_t stream) {
    const float* enc     = (const float*)d_in[0];
    const float* dec_z   = (const float*)d_in[2];
    const float* att_prev= (const float*)d_in[3];
    const float* Wq      = (const float*)d_in[4];
    const float* bq      = (const float*)d_in[5];
    const float* Wk      = (const float*)d_in[6];
    const float* Wv      = (const float*)d_in[7];
    const float* g_w     = (const float*)d_in[8];
    const float* Watt    = (const float*)d_in[10];
    const float* Wo      = (const float*)d_in[11];
    const float* cw0     = (const float*)d_in[12];
    const float* cw1     = (const float*)d_in[13];
    const float* cw2     = (const float*)d_in[14];
    const float* cw3     = (const float*)d_in[15];

    float* ws    = (float*)d_ws;
    float* q_buf = ws;                          // 65536 f
    float* e_buf = ws + 65536;                  // 128000 f
    float* c_buf = ws + 193536;                 // 65536 f
    float* ctx   = ws + 259072;                 // 131072 f   (zeroed through here)
    unsigned short* enc16 = (unsigned short*)(ws + 390144);   // 32*1024*1024 bf16
    unsigned short* Wkt   = (unsigned short*)(ws + 17167360); // 4*512*1024 bf16
    __hip_bfloat16* WWt   = (__hip_bfloat16*)(ws + 18215936); // 4*512*256 bf16
    float* outp  = (float*)d_out;               // 32768 f
    float* wout  = outp + 32768;                // 128000 f

    // zero atomic-accumulated buffers: q, e, c, ctx, out
    hipMemsetAsync(ws, 0, (size_t)390144 * sizeof(float), stream);
    hipMemsetAsync(d_out, 0, (size_t)32768 * sizeof(float), stream);

    enc_cvt_kernel<<<dim3(Tt, Bb), 256, 0, stream>>>(enc, enc16);
    wkt_kernel<<<dim3(8, 16, 4), 256, 0, stream>>>(Wk, Wkt);
    ww_kernel<<<dim3(KPAD, 4), 256, 0, stream>>>(cw0, cw1, cw2, cw3, Watt, WWt);
    q_kernel<<<dim3(4, 16, 4), 256, 0, stream>>>(dec_z, Wq, q_buf);
    e_kernel<<<4096, 256, 0, stream>>>(enc16, Wkt, att_prev, WWt,
                                       q_buf, bq, g_w, e_buf);
    softmax_kernel<<<128, 256, 0, stream>>>(e_buf, wout);
    ctx_kernel<<<dim3(8, 32, 4), 256, 0, stream>>>(wout, enc16, ctx);
    c_kernel<<<dim3(4, 16, 4), 256, 0, stream>>>(ctx, Wv, c_buf);
    out_kernel<<<dim3(8, 32), 256, 0, stream>>>(c_buf, Wo, outp);
}